// Round 5
// baseline (2737.051 us; speedup 1.0000x reference)
//
#include <hip/hip_runtime.h>
#include <stdint.h>

// LSTM autoencoder: B=256,T=256,D=128,H=256, gate order i,f,g,o.
// R5: recurrence latency model fixed. Register file was exactly full (Areg 128 regs in
// AGPRs + 128 VGPRs) -> compiler JIT-loaded every non-resident frag with a full wait,
// serializing ~16-37 loads x 120-250 cyc = the invariant ~11k cyc/step. Now: KCR=2
// (64 regs resident), stream kc 2..7 from L2 (only 32 CUs active -> ~450 B/cyc/CU L2 BW,
// latency hidden by batched full-q prefetch with ~80 free VGPRs). h stored in MFMA-frag
// chunk order -> conflict-free b128 reads (old pad gave 8-way). xp prefetched a full
// step ahead. LDS = h double-buffer only (16 KB enc / 8 KB dec).

#define B_N 256
#define T_N 256
#define D_N 128
#define H_N 256

typedef __attribute__((ext_vector_type(8))) short bf16x8;  // MFMA A/B frag (4 VGPRs)
typedef __attribute__((ext_vector_type(4))) float f32x4;   // MFMA C/D frag
typedef unsigned short u16;
typedef unsigned int u32;

__device__ __forceinline__ float bflo(u32 u){ return __uint_as_float(u << 16); }
__device__ __forceinline__ float bfhi(u32 u){ return __uint_as_float(u & 0xffff0000u); }
__device__ __forceinline__ u32 f2bf_bits(float f){ u32 u = __float_as_uint(f); return (u + 0x7fffu + ((u >> 16) & 1u)) >> 16; }
__device__ __forceinline__ u32 pack2(float lo, float hi){ return f2bf_bits(lo) | (f2bf_bits(hi) << 16); }
__device__ __forceinline__ float sigm(float x){ return __builtin_amdgcn_rcpf(1.f + __expf(-x)); }
__device__ __forceinline__ float tanh_f(float x){ return 1.f - 2.f * __builtin_amdgcn_rcpf(1.f + __expf(2.f * x)); }
__device__ __forceinline__ float xpj(uint2 r, int j){
  return j == 0 ? bflo(r.x) : j == 1 ? bfhi(r.x) : j == 2 ? bflo(r.y) : bfhi(r.y);
}

// ---------- prep kernels ----------
__global__ void k_cvt(const float* __restrict__ src, u16* __restrict__ dst, int n){
  int i = (blockIdx.x * blockDim.x + threadIdx.x) * 4;
  if (i >= n) return;
  float4 v = *(const float4*)(src + i);
  uint2 o; o.x = pack2(v.x, v.y); o.y = pack2(v.z, v.w);
  *(uint2*)(dst + i) = o;
}

// Row permutation p -> orig so that wave v (of 1<<VB waves) owns rows
// [v*4U,(v+1)*4U) = {i,f,g,o} x units[v*U,(v+1)*U), U = 1<<UB units/wave.
// p = (v << (UB+2)) | (g << UB) | uo  ;  orig = (g << (UB+VB)) | (v << UB) | uo
__global__ void k_permW(const float* __restrict__ W, u16* __restrict__ Wp, int K, int UB, int VB){
  int p = blockIdx.x;
  int uo = p & ((1 << UB) - 1), g = (p >> UB) & 3, v = p >> (UB + 2);
  int orig = (g << (UB + VB)) | (v << UB) | uo;
  for (int k = threadIdx.x; k < K; k += blockDim.x)
    Wp[(size_t)p * K + k] = (u16)f2bf_bits(W[(size_t)orig * K + k]);
}

__global__ void k_permB(const float* __restrict__ b1, const float* __restrict__ b2,
                        float* __restrict__ bp, int P, int UB, int VB){
  for (int p = threadIdx.x; p < P; p += blockDim.x){
    int uo = p & ((1 << UB) - 1), g = (p >> UB) & 3, v = p >> (UB + 2);
    int orig = (g << (UB + VB)) | (v << UB) | uo;
    bp[p] = b1[orig] + b2[orig];
  }
}

// ---------- input-projection GEMM: out[m,n] = sum_k A[m,k]*W[n,k] + bias[n] (bf16 in, bf16 out) ----------
template<int KTOT, bool ENC_MAP>
__global__ __launch_bounds__(256, 1) void k_xproj(const u16* __restrict__ A, const u16* __restrict__ W,
                                                  const float* __restrict__ bias, u16* __restrict__ outp, int N){
  __shared__ u16 As[64][72];
  __shared__ u16 Ws[64][72];
  const int tid = threadIdx.x, l = tid & 63, v = tid >> 6;
  const int lb = l & 15, lq = l >> 4;
  const int m0 = blockIdx.x * 64, n0 = blockIdx.y * 64;
  f32x4 acc[4];
#pragma unroll
  for (int nt = 0; nt < 4; nt++){ float bv = bias[n0 + nt * 16 + lb]; f32x4 t = {bv, bv, bv, bv}; acc[nt] = t; }
  const int r = tid >> 3, c8 = (tid & 7) * 8;
  for (int kb = 0; kb < KTOT / 64; ++kb){
    __syncthreads();
    *(bf16x8*)&As[r][c8]      = *(const bf16x8*)&A[(size_t)(m0 + r) * KTOT + kb * 64 + c8];
    *(bf16x8*)&As[r + 32][c8] = *(const bf16x8*)&A[(size_t)(m0 + r + 32) * KTOT + kb * 64 + c8];
    *(bf16x8*)&Ws[r][c8]      = *(const bf16x8*)&W[(size_t)(n0 + r) * KTOT + kb * 64 + c8];
    *(bf16x8*)&Ws[r + 32][c8] = *(const bf16x8*)&W[(size_t)(n0 + r + 32) * KTOT + kb * 64 + c8];
    __syncthreads();
#pragma unroll
    for (int kc = 0; kc < 2; kc++){
      bf16x8 af = *(const bf16x8*)&As[v * 16 + lb][kc * 32 + lq * 8];
#pragma unroll
      for (int nt = 0; nt < 4; nt++){
        bf16x8 wf = *(const bf16x8*)&Ws[nt * 16 + lb][kc * 32 + lq * 8];
        acc[nt] = __builtin_amdgcn_mfma_f32_16x16x32_bf16(af, wf, acc[nt], 0, 0, 0);
      }
    }
  }
#pragma unroll
  for (int nt = 0; nt < 4; nt++){
    const int n = n0 + nt * 16 + lb;
#pragma unroll
    for (int j = 0; j < 4; j++){
      const int m = m0 + v * 16 + lq * 4 + j;
      size_t o;
      if (ENC_MAP) o = ((size_t)(m & 255) * 256 + (size_t)(m >> 8)) * (size_t)N + n; // m=b*T+t -> [t][b][N]
      else         o = (size_t)m * (size_t)N + n;                                    // m=t*B+b -> [t][b][N]
      outp[o] = (u16)f2bf_bits(acc[nt][j]);
    }
  }
}

// ---------- persistent recurrence ----------
// Grid 32 wgs; wg owns batch slice of 8 (MFMA N-cols 8..15 dead). Weights = A operand
// (M = gate rows, pre-permuted), h = B operand (N = batch). Wave v owns rows
// [v*NMT*16, (v+1)*NMT*16). kc < KCR resident in regs; kc >= KCR streamed from L2 each
// step as a full-q batch of loads (L2 BW/CU is huge at 32 active CUs; batching hides
// latency once instead of serializing per-load waits).
// h in LDS in MFMA-frag chunk order: chunk kc (1024 B) holds lane-chunks of 16 B at
// slot (lq*16+lb) -> Bh reads are stride-1 b128 (bank-conflict-free); write addr for
// unit u0, batch lb: byte (u0>>5)*1024 + (((u0>>3)&3)*16+lb)*16 + (u0&7)*2 (2-way, free).
// Double-buffered (read t&1, write (t&1)^1), ONE barrier/step. xp prefetched 1 full step.
template<int KDIM, int NWAVE, int NMT, int NKC, int NQ, int KCR, bool IS_DEC>
__global__ __launch_bounds__(NWAVE * 64, 1) void k_rec(const u16* __restrict__ Wp, const u16* __restrict__ xp,
                                                       u16* __restrict__ enc_out, float* __restrict__ out){
  constexpr int NROWS = NWAVE * NMT * 16;   // total gate rows (4*Hout)
  constexpr int NSTR = NKC - KCR;           // streamed k-chunks per q
  static_assert(NMT == 4 * NQ, "tiles = 4 gates x NQ unit groups");
  extern __shared__ u16 smem[];             // [2][NKC*512] u16
  const int tid = threadIdx.x, l = tid & 63, v = tid >> 6;
  const int lb = l & 15, lq = l >> 4;
  const int b0 = blockIdx.x * 8;

  // per-mt weight base pointers (lane-dependent row, frag layout A[m=lane&15][k=quad*8+j])
  const u16* wbase[NMT];
#pragma unroll
  for (int mt = 0; mt < NMT; ++mt)
    wbase[mt] = Wp + (size_t)(v * (NMT * 16) + mt * 16 + lb) * KDIM + lq * 8;

  // resident frags: kc < KCR, all mt
  bf16x8 Areg[KCR * NMT];
#pragma unroll
  for (int kc = 0; kc < KCR; ++kc)
#pragma unroll
    for (int mt = 0; mt < NMT; ++mt)
      Areg[kc * NMT + mt] = *(const bf16x8*)(wbase[mt] + kc * 32);

  for (int i = tid; i < 2 * NKC * 512; i += NWAVE * 64) smem[i] = 0;   // h(-1)=0; lb>=8 slots stay 0
  float c[NQ][4];
#pragma unroll
  for (int q = 0; q < NQ; q++)
#pragma unroll
    for (int j = 0; j < 4; j++) c[q][j] = 0.f;

  // xp prefetch for t=0
  uint2 xr[NQ][4];
#pragma unroll
  for (int q = 0; q < NQ; ++q)
#pragma unroll
    for (int g = 0; g < 4; ++g){
      uint2 z; z.x = 0; z.y = 0;
      if (lb < 8) z = *(const uint2*)(xp + (size_t)(b0 + lb) * NROWS + v * (NMT * 16) + (g * NQ + q) * 16 + lq * 4);
      xr[q][g] = z;
    }
  __syncthreads();

  for (int t = 0; t < T_N; ++t){
    const u16* hrd = smem + (size_t)(t & 1) * (NKC * 512);
    u16*       hwr = smem + (size_t)((t & 1) ^ 1) * (NKC * 512);

    // h(t-1) B-frags: conflict-free stride-1 b128 reads
    bf16x8 Bh[NKC];
#pragma unroll
    for (int kc = 0; kc < NKC; ++kc)
      Bh[kc] = *(const bf16x8*)&hrd[kc * 512 + (lq * 16 + lb) * 8];

    // xp prefetch for t+1 (full-step lead: HBM latency + barrier drain hidden)
    uint2 xn[NQ][4];
    {
      const int tn = (t + 1 < T_N) ? t + 1 : t;
      const u16* xptn = xp + (size_t)(tn * 256 + b0 + lb) * NROWS + v * (NMT * 16) + lq * 4;
#pragma unroll
      for (int q = 0; q < NQ; ++q)
#pragma unroll
        for (int g = 0; g < 4; ++g){
          uint2 z; z.x = 0; z.y = 0;
          if (lb < 8) z = *(const uint2*)(xptn + (size_t)((g * NQ + q) * 16));
          xn[q][g] = z;
        }
    }

    uint2  hsv[NQ];   // packed h for post-barrier global store (enc)
    float4 osv[NQ];   // fp32 out for post-barrier global store (dec)
#pragma unroll
    for (int q = 0; q < NQ; ++q){
      // streamed weight frags for this q: batch-issue all loads (L2-hot Whh)
      bf16x8 Astr[(NSTR > 0) ? NSTR * 4 : 1];
      if (NSTR > 0){
#pragma unroll
        for (int kk = 0; kk < NSTR; ++kk)
#pragma unroll
          for (int g = 0; g < 4; ++g)
            Astr[kk * 4 + g] = *(const bf16x8*)(wbase[g * NQ + q] + (KCR + kk) * 32);
      }
      f32x4 acc[4];
#pragma unroll
      for (int g = 0; g < 4; ++g){ f32x4 zz = {0.f, 0.f, 0.f, 0.f}; acc[g] = zz; }
#pragma unroll
      for (int kc = 0; kc < NKC; ++kc)
#pragma unroll
        for (int g = 0; g < 4; ++g){
          const int mt = g * NQ + q;
          bf16x8 af = (kc < KCR) ? Areg[kc * NMT + mt] : Astr[(kc - KCR) * 4 + g];
          acc[g] = __builtin_amdgcn_mfma_f32_16x16x32_bf16(af, Bh[kc], acc[g], 0, 0, 0);
        }
      // gates: acc[0..3] + xp = i,f,g,o pre-acts for same (b,u) per lane/reg
      float hv[4];
#pragma unroll
      for (int j = 0; j < 4; ++j){
        float iv = sigm(acc[0][j] + xpj(xr[q][0], j));
        float fv = sigm(acc[1][j] + xpj(xr[q][1], j));
        float gv = tanh_f(acc[2][j] + xpj(xr[q][2], j));
        float ov = sigm(acc[3][j] + xpj(xr[q][3], j));
        float cc = fv * c[q][j] + iv * gv;
        c[q][j] = cc;
        hv[j] = ov * tanh_f(cc);
      }
      if (lb < 8){
        const int u0 = v * (NQ * 16) + q * 16 + lq * 4;
        uint2 hp; hp.x = pack2(hv[0], hv[1]); hp.y = pack2(hv[2], hv[3]);
        *(uint2*)&hwr[(u0 >> 5) * 512 + (((u0 >> 3) & 3) * 16 + lb) * 8 + (u0 & 7)] = hp;
        if (!IS_DEC) hsv[q] = hp;
        else         osv[q] = make_float4(hv[0], hv[1], hv[2], hv[3]);
      }
    }
#pragma unroll
    for (int q = 0; q < NQ; ++q)
#pragma unroll
      for (int g = 0; g < 4; ++g) xr[q][g] = xn[q][g];
    __syncthreads();   // h(t) visible; global stores AFTER so the drain overlaps next step
    if (lb < 8){
#pragma unroll
      for (int q = 0; q < NQ; ++q){
        const int u0 = v * (NQ * 16) + q * 16 + lq * 4;
        if (!IS_DEC) *(uint2*)(enc_out + (size_t)(t * 256 + b0 + lb) * KDIM + u0) = hsv[q];
        else         *(float4*)(out + ((size_t)(b0 + lb) * T_N + t) * D_N + u0) = osv[q];
      }
    }
  }
}

extern "C" void kernel_launch(void* const* d_in, const int* in_sizes, int n_in,
                              void* d_out, int out_size, void* d_ws, size_t ws_size,
                              hipStream_t stream){
  const float* x    = (const float*)d_in[0];
  const float* eWih = (const float*)d_in[1];
  const float* eWhh = (const float*)d_in[2];
  const float* ebih = (const float*)d_in[3];
  const float* ebhh = (const float*)d_in[4];
  const float* dWih = (const float*)d_in[5];
  const float* dWhh = (const float*)d_in[6];
  const float* dbih = (const float*)d_in[7];
  const float* dbhh = (const float*)d_in[8];
  float* out = (float*)d_out;

  char* w = (char*)d_ws;
  size_t off = 0;
  auto carve = [&](size_t bytes) -> void* { void* p = w + off; off = (off + bytes + 255) & ~(size_t)255; return p; };
  u16*   xb    = (u16*)carve((size_t)B_N * T_N * D_N * 2);          // x in bf16
  u16*   WihEp = (u16*)carve((size_t)4 * H_N * D_N * 2);            // permuted enc Wih (UB=5,VB=3)
  u16*   WhhEp = (u16*)carve((size_t)4 * H_N * H_N * 2);            // permuted enc Whh (UB=5,VB=3)
  u16*   WihDp = (u16*)carve((size_t)4 * D_N * H_N * 2);            // permuted dec Wih (UB=4,VB=3)
  u16*   WhhDp = (u16*)carve((size_t)4 * D_N * D_N * 2);            // permuted dec Whh (UB=4,VB=3)
  float* bE    = (float*)carve((size_t)4 * H_N * 4);
  float* bD    = (float*)carve((size_t)4 * D_N * 4);
  u16*   xpE   = (u16*)carve((size_t)T_N * B_N * 4 * H_N * 2);      // [T][B][4H] permuted, bf16
  u16*   enc   = (u16*)carve((size_t)T_N * B_N * H_N * 2);          // encoded [T][B][H] bf16
  u16*   xpD   = (u16*)carve((size_t)T_N * B_N * 4 * D_N * 2);      // [T][B][4D] permuted, bf16
  (void)ws_size; (void)in_sizes; (void)n_in; (void)out_size;

  hipLaunchKernelGGL(k_cvt, dim3((B_N * T_N * D_N) / 1024), dim3(256), 0, stream, x, xb, B_N * T_N * D_N);
  hipLaunchKernelGGL(k_permW, dim3(1024), dim3(128), 0, stream, eWih, WihEp, 128, 5, 3);
  hipLaunchKernelGGL(k_permW, dim3(1024), dim3(128), 0, stream, eWhh, WhhEp, 256, 5, 3);
  hipLaunchKernelGGL(k_permW, dim3(512),  dim3(128), 0, stream, dWih, WihDp, 256, 4, 3);
  hipLaunchKernelGGL(k_permW, dim3(512),  dim3(128), 0, stream, dWhh, WhhDp, 128, 4, 3);
  hipLaunchKernelGGL(k_permB, dim3(1), dim3(256), 0, stream, ebih, ebhh, bE, 1024, 5, 3);
  hipLaunchKernelGGL(k_permB, dim3(1), dim3(256), 0, stream, dbih, dbhh, bD, 512, 4, 3);

  // enc x-proj: [65536,1024] = xb @ WihEp^T  (M rows are b*T+t -> stored [t][b][p])
  hipLaunchKernelGGL((k_xproj<128, true>),  dim3(1024, 16), dim3(256), 0, stream, xb,  WihEp, bE, xpE, 1024);
  // enc recurrence: 8 waves (2/SIMD), NMT=8, kc 0-1 regs, kc 2-7 L2-streamed; LDS 16 KB (h dbuf)
  hipLaunchKernelGGL((k_rec<256, 8, 8, 8, 2, 2, false>), dim3(32), dim3(512),
                     2 * 8 * 1024, stream, WhhEp, xpE, enc, (float*)nullptr);
  // dec x-proj: [65536,512] = enc @ WihDp^T (M rows are t*B+b -> stored [t][b][N])
  hipLaunchKernelGGL((k_xproj<256, false>), dim3(1024, 8),  dim3(256), 0, stream, enc, WihDp, bD, xpD, 512);
  // dec recurrence: 8 waves (2/SIMD), NMT=4, all 16 frags in regs; LDS 8 KB (h dbuf); fp32 out
  hipLaunchKernelGGL((k_rec<128, 8, 4, 4, 1, 4, true>),  dim3(32), dim3(512),
                     2 * 4 * 1024, stream, WhhDp, xpD, (u16*)nullptr, out);
}

// Round 6
// 1837.927 us; speedup vs baseline: 1.4892x; 1.4892x over previous
//
#include <hip/hip_runtime.h>
#include <stdint.h>

// LSTM autoencoder: B=256,T=256,D=128,H=256, gate order i,f,g,o.
// R6: established empirically (R3/R4/R5): per-CU vector-load ingest ~34-60 B/cyc makes
// weight streaming untenable -> full on-chip residency, 4 waves 1/SIMD (R3 shape) is the
// only feasible config. This round: (a) enc = R3 + conflict-free h chunk layout (R5-
// proven) + acc-init-from-xp (kills zero-init+post-add VALU) + staggered xp loads;
// (b) dec recurrence fuses xprojD: B = [enc_h(t) K=256 | dec_h(t-1) K=128] vs
// [WihD|WhhD] (384-k rows, 96 frags/wave resident) -> xprojD kernel + 134 MB xpD
// round-trip eliminated; bias via acc-init; enc_h(t+1) prefetched into regs each step.

#define B_N 256
#define T_N 256
#define D_N 128
#define H_N 256

typedef __attribute__((ext_vector_type(8))) short bf16x8;  // MFMA A/B frag (4 VGPRs)
typedef __attribute__((ext_vector_type(4))) float f32x4;   // MFMA C/D frag
typedef unsigned short u16;
typedef unsigned int u32;

__device__ __forceinline__ float bflo(u32 u){ return __uint_as_float(u << 16); }
__device__ __forceinline__ float bfhi(u32 u){ return __uint_as_float(u & 0xffff0000u); }
__device__ __forceinline__ u32 f2bf_bits(float f){ u32 u = __float_as_uint(f); return (u + 0x7fffu + ((u >> 16) & 1u)) >> 16; }
__device__ __forceinline__ u32 pack2(float lo, float hi){ return f2bf_bits(lo) | (f2bf_bits(hi) << 16); }
__device__ __forceinline__ float sigm(float x){ return __builtin_amdgcn_rcpf(1.f + __expf(-x)); }
__device__ __forceinline__ float tanh_f(float x){ return 1.f - 2.f * __builtin_amdgcn_rcpf(1.f + __expf(2.f * x)); }

// ---------- prep kernels ----------
__global__ void k_cvt(const float* __restrict__ src, u16* __restrict__ dst, int n){
  int i = (blockIdx.x * blockDim.x + threadIdx.x) * 4;
  if (i >= n) return;
  float4 v = *(const float4*)(src + i);
  uint2 o; o.x = pack2(v.x, v.y); o.y = pack2(v.z, v.w);
  *(uint2*)(dst + i) = o;
}

// Row permutation p -> orig so that wave v (of 1<<VB waves) owns rows
// [v*4U,(v+1)*4U) = {i,f,g,o} x units[v*U,(v+1)*U), U = 1<<UB units/wave.
// orig = (g << (UB+VB)) | (v << UB) | uo. Dst row stride DSTK, column offset KOFF
// (for concatenating [Wih|Whh] into one 384-k row).
__global__ void k_permW(const float* __restrict__ W, u16* __restrict__ Wp, int K, int UB, int VB,
                        int DSTK, int KOFF){
  int p = blockIdx.x;
  int uo = p & ((1 << UB) - 1), g = (p >> UB) & 3, v = p >> (UB + 2);
  int orig = (g << (UB + VB)) | (v << UB) | uo;
  for (int k = threadIdx.x; k < K; k += blockDim.x)
    Wp[(size_t)p * DSTK + KOFF + k] = (u16)f2bf_bits(W[(size_t)orig * K + k]);
}

__global__ void k_permB(const float* __restrict__ b1, const float* __restrict__ b2,
                        float* __restrict__ bp, int P, int UB, int VB){
  for (int p = threadIdx.x; p < P; p += blockDim.x){
    int uo = p & ((1 << UB) - 1), g = (p >> UB) & 3, v = p >> (UB + 2);
    int orig = (g << (UB + VB)) | (v << UB) | uo;
    bp[p] = b1[orig] + b2[orig];
  }
}

// ---------- enc input-projection GEMM: out[m,n] = sum_k A[m,k]*W[n,k] + bias[n] ----------
__global__ __launch_bounds__(256, 1) void k_xproj(const u16* __restrict__ A, const u16* __restrict__ W,
                                                  const float* __restrict__ bias, u16* __restrict__ outp){
  constexpr int KTOT = 128, N = 1024;
  __shared__ u16 As[64][72];
  __shared__ u16 Ws[64][72];
  const int tid = threadIdx.x, l = tid & 63, v = tid >> 6;
  const int lb = l & 15, lq = l >> 4;
  const int m0 = blockIdx.x * 64, n0 = blockIdx.y * 64;
  f32x4 acc[4];
#pragma unroll
  for (int nt = 0; nt < 4; nt++){ float bv = bias[n0 + nt * 16 + lb]; f32x4 t = {bv, bv, bv, bv}; acc[nt] = t; }
  const int r = tid >> 3, c8 = (tid & 7) * 8;
  for (int kb = 0; kb < KTOT / 64; ++kb){
    __syncthreads();
    *(bf16x8*)&As[r][c8]      = *(const bf16x8*)&A[(size_t)(m0 + r) * KTOT + kb * 64 + c8];
    *(bf16x8*)&As[r + 32][c8] = *(const bf16x8*)&A[(size_t)(m0 + r + 32) * KTOT + kb * 64 + c8];
    *(bf16x8*)&Ws[r][c8]      = *(const bf16x8*)&W[(size_t)(n0 + r) * KTOT + kb * 64 + c8];
    *(bf16x8*)&Ws[r + 32][c8] = *(const bf16x8*)&W[(size_t)(n0 + r + 32) * KTOT + kb * 64 + c8];
    __syncthreads();
#pragma unroll
    for (int kc = 0; kc < 2; kc++){
      bf16x8 af = *(const bf16x8*)&As[v * 16 + lb][kc * 32 + lq * 8];
#pragma unroll
      for (int nt = 0; nt < 4; nt++){
        bf16x8 wf = *(const bf16x8*)&Ws[nt * 16 + lb][kc * 32 + lq * 8];
        acc[nt] = __builtin_amdgcn_mfma_f32_16x16x32_bf16(af, wf, acc[nt], 0, 0, 0);
      }
    }
  }
#pragma unroll
  for (int nt = 0; nt < 4; nt++){
    const int n = n0 + nt * 16 + lb;
#pragma unroll
    for (int j = 0; j < 4; j++){
      const int m = m0 + v * 16 + lq * 4 + j;  // m = b*T + t
      size_t o = ((size_t)(m & 255) * 256 + (size_t)(m >> 8)) * (size_t)N + n;  // [t][b][N]
      outp[o] = (u16)f2bf_bits(acc[nt][j]);
    }
  }
}

// ---------- encoder recurrence (persistent, 32 wgs x 4 waves, full residency) ----------
// h chunk layout (conflict-free, R5-proven): buffer = NKC chunks of 1024 B; chunk kc,
// slot s=lq*16+lb holds B-frag bytes h[b=lb][k=kc*32+lq*8 .. +8]. Slots with (s&15)>=8
// are zero forever -> MFMA cols 8..15 get h=0 (results discarded).
__global__ __launch_bounds__(256, 1) void k_renc(const u16* __restrict__ Wp, const u16* __restrict__ xp,
                                                 u16* __restrict__ enc_out){
  constexpr int NMT = 16, NKC = 8, NQ = 4, F_REG = 93, F_LDS = 35;
  extern __shared__ u16 smem[];
  u16* hbuf = smem;                        // [2][NKC*512] u16
  u16* al   = smem + 2 * NKC * 512;        // [4][F_LDS][512] u16
  const int tid = threadIdx.x, l = tid & 63, v = tid >> 6;
  const int lb = l & 15, lq = l >> 4;
  const int b0 = blockIdx.x * 8;
  const u16* wwave = Wp + (size_t)(v * 256 + lb) * 256 + lq * 8;
  u16* alw = al + v * F_LDS * 512;

  // one-time weight residency: frag layout A[m=lane&15][k=quad*8+j]
  bf16x8 Areg[F_REG];
#pragma unroll
  for (int kc = 0; kc < NKC; ++kc)
#pragma unroll
    for (int mt = 0; mt < NMT; ++mt){
      const int idx = kc * NMT + mt;
      const u16* src = wwave + (size_t)(mt * 16) * 256 + kc * 32;
      if (idx < F_REG) Areg[idx] = *(const bf16x8*)src;
      else             *(bf16x8*)&alw[(idx - F_REG) * 512 + l * 8] = *(const bf16x8*)src;
    }
  for (int i = tid; i < 2 * NKC * 512; i += 256) hbuf[i] = 0;  // h(-1)=0, dead slots stay 0
  float c[NQ][4];
#pragma unroll
  for (int q = 0; q < NQ; q++)
#pragma unroll
    for (int j = 0; j < 4; j++) c[q][j] = 0.f;
  __syncthreads();

  for (int t = 0; t < T_N; ++t){
    const u16* hrd = hbuf + (size_t)(t & 1) * (NKC * 512);
    u16*       hwr = hbuf + (size_t)((t & 1) ^ 1) * (NKC * 512);
    const u16* xpt = xp + ((size_t)(t * 256 + b0 + lb)) * 1024 + v * 256 + lq * 4;

    // h(t-1) B-frags: conflict-free stride-1 b128 reads, no predication
    bf16x8 Bh[NKC];
#pragma unroll
    for (int kc = 0; kc < NKC; ++kc)
      Bh[kc] = *(const bf16x8*)&hrd[kc * 512 + (lq * 16 + lb) * 8];

    // xp for q=0,1 at step start; q=2,3 loaded mid-chain (consumed >=2 MFMA chains later)
    uint2 xr[NQ][4];
#pragma unroll
    for (int q = 0; q < 2; ++q)
#pragma unroll
      for (int g = 0; g < 4; ++g){
        uint2 z; z.x = 0; z.y = 0;
        if (lb < 8) z = *(const uint2*)(xpt + (size_t)((g * NQ + q) * 16));
        xr[q][g] = z;
      }

    uint2 hsv[NQ];
#pragma unroll
    for (int q = 0; q < NQ; ++q){
      if (q == 1){
#pragma unroll
        for (int qq = 2; qq < 4; ++qq)
#pragma unroll
          for (int g = 0; g < 4; ++g){
            uint2 z; z.x = 0; z.y = 0;
            if (lb < 8) z = *(const uint2*)(xpt + (size_t)((g * NQ + qq) * 16));
            xr[qq][g] = z;
          }
      }
      // acc init = xp (bias+input proj); lb>=8 lanes get 0 (xr predicated to 0)
      f32x4 acc[4];
#pragma unroll
      for (int g = 0; g < 4; ++g){
        acc[g][0] = bflo(xr[q][g].x); acc[g][1] = bfhi(xr[q][g].x);
        acc[g][2] = bflo(xr[q][g].y); acc[g][3] = bfhi(xr[q][g].y);
      }
#pragma unroll
      for (int kc = 0; kc < NKC; ++kc)
#pragma unroll
        for (int g = 0; g < 4; ++g){
          const int idx = kc * NMT + g * NQ + q;
          bf16x8 af;
          if (idx < F_REG) af = Areg[idx];
          else             af = *(const bf16x8*)&alw[(idx - F_REG) * 512 + l * 8];
          acc[g] = __builtin_amdgcn_mfma_f32_16x16x32_bf16(af, Bh[kc], acc[g], 0, 0, 0);
        }
      // gates: acc[0..3] = i,f,g,o pre-acts for same (b,u) per lane/reg
      float hv[4];
#pragma unroll
      for (int j = 0; j < 4; ++j){
        float iv = sigm(acc[0][j]);
        float fv = sigm(acc[1][j]);
        float gv = tanh_f(acc[2][j]);
        float ov = sigm(acc[3][j]);
        float cc = fv * c[q][j] + iv * gv;
        c[q][j] = cc;
        hv[j] = ov * tanh_f(cc);
      }
      const int u0 = v * 64 + q * 16 + lq * 4;
      uint2 hp; hp.x = pack2(hv[0], hv[1]); hp.y = pack2(hv[2], hv[3]);
      if (lb < 8)
        *(uint2*)&hwr[(u0 >> 5) * 512 + (((u0 >> 3) & 3) * 16 + lb) * 8 + (u0 & 7)] = hp;
      hsv[q] = hp;
    }
    __syncthreads();   // h(t) visible; global stores after -> drain overlaps next step
    if (lb < 8){
#pragma unroll
      for (int q = 0; q < NQ; ++q){
        const int u0 = v * 64 + q * 16 + lq * 4;
        *(uint2*)(enc_out + (size_t)(t * 256 + b0 + lb) * 256 + u0) = hsv[q];
      }
    }
  }
}

// ---------- decoder recurrence with fused x-projection ----------
// B-operand = [enc_h(t) (kc 0..7, global, prefetched 1 step ahead) | dec_h(t-1)
// (kc 8..11, LDS chunks)]; A = concatenated [WihD|WhhD] permuted rows (384-k).
// acc init = permuted bias. Output fp32 [B][T][D].
__global__ __launch_bounds__(256, 1) void k_rdec(const u16* __restrict__ Wc, const float* __restrict__ bD,
                                                 const u16* __restrict__ enc, float* __restrict__ out){
  constexpr int NMT = 8, NKC = 12, NKH = 4, NQ = 2, F_REG = 72, F_LDS = 24;
  extern __shared__ u16 smem[];
  u16* hbuf = smem;                         // [2][NKH*512] u16
  u16* al   = smem + 2 * NKH * 512;         // [4][F_LDS][512] u16
  const int tid = threadIdx.x, l = tid & 63, v = tid >> 6;
  const int lb = l & 15, lq = l >> 4;
  const int b0 = blockIdx.x * 8;
  const int brow = (b0 + lb < 256) ? (b0 + lb) : 255;  // clamp; cols>=8 are discarded anyway
  const u16* wwave = Wc + (size_t)(v * 128 + lb) * 384 + lq * 8;
  u16* alw = al + v * F_LDS * 512;

  bf16x8 Areg[F_REG];
#pragma unroll
  for (int kc = 0; kc < NKC; ++kc)
#pragma unroll
    for (int mt = 0; mt < NMT; ++mt){
      const int idx = kc * NMT + mt;
      const u16* src = wwave + (size_t)(mt * 16) * 384 + kc * 32;
      if (idx < F_REG) Areg[idx] = *(const bf16x8*)src;
      else             *(bf16x8*)&alw[(idx - F_REG) * 512 + l * 8] = *(const bf16x8*)src;
    }
  float4 b4[NQ][4];
#pragma unroll
  for (int q = 0; q < NQ; ++q)
#pragma unroll
    for (int g = 0; g < 4; ++g)
      b4[q][g] = *(const float4*)&bD[v * 128 + g * 32 + q * 16 + lq * 4];
  for (int i = tid; i < 2 * NKH * 512; i += 256) hbuf[i] = 0;
  float c[NQ][4];
#pragma unroll
  for (int q = 0; q < NQ; q++)
#pragma unroll
    for (int j = 0; j < 4; j++) c[q][j] = 0.f;

  // prefetch enc_h(0) B-frags from global (B[k=quad*8+j][n=lane&15] = enc[t][b=n][k])
  bf16x8 Be[8];
  {
    const u16* e0 = enc + (size_t)brow * 256 + lq * 8;
#pragma unroll
    for (int kc = 0; kc < 8; ++kc) Be[kc] = *(const bf16x8*)(e0 + kc * 32);
  }
  __syncthreads();

  for (int t = 0; t < T_N; ++t){
    const u16* hrd = hbuf + (size_t)(t & 1) * (NKH * 512);
    u16*       hwr = hbuf + (size_t)((t & 1) ^ 1) * (NKH * 512);

    // prefetch enc_h(t+1) now (consumed next step: full-step latency lead)
    bf16x8 Bn[8];
    {
      const int tn = (t + 1 < T_N) ? t + 1 : t;
      const u16* en = enc + (size_t)(tn * 256 + brow) * 256 + lq * 8;
#pragma unroll
      for (int kc = 0; kc < 8; ++kc) Bn[kc] = *(const bf16x8*)(en + kc * 32);
    }
    // dec_h(t-1) B-frags from LDS chunks
    bf16x8 Bd[NKH];
#pragma unroll
    for (int kc = 0; kc < NKH; ++kc)
      Bd[kc] = *(const bf16x8*)&hrd[kc * 512 + (lq * 16 + lb) * 8];

    float4 osv[NQ];
#pragma unroll
    for (int q = 0; q < NQ; ++q){
      f32x4 acc[4];
#pragma unroll
      for (int g = 0; g < 4; ++g){
        acc[g][0] = b4[q][g].x; acc[g][1] = b4[q][g].y;
        acc[g][2] = b4[q][g].z; acc[g][3] = b4[q][g].w;
      }
#pragma unroll
      for (int kc = 0; kc < NKC; ++kc)
#pragma unroll
        for (int g = 0; g < 4; ++g){
          const int idx = kc * NMT + g * NQ + q;
          bf16x8 af;
          if (idx < F_REG) af = Areg[idx];
          else             af = *(const bf16x8*)&alw[(idx - F_REG) * 512 + l * 8];
          bf16x8 bf = (kc < 8) ? Be[(kc < 8) ? kc : 0] : Bd[(kc >= 8) ? (kc - 8) : 0];
          acc[g] = __builtin_amdgcn_mfma_f32_16x16x32_bf16(af, bf, acc[g], 0, 0, 0);
        }
      float hv[4];
#pragma unroll
      for (int j = 0; j < 4; ++j){
        float iv = sigm(acc[0][j]);
        float fv = sigm(acc[1][j]);
        float gv = tanh_f(acc[2][j]);
        float ov = sigm(acc[3][j]);
        float cc = fv * c[q][j] + iv * gv;
        c[q][j] = cc;
        hv[j] = ov * tanh_f(cc);
      }
      const int u0 = v * 32 + q * 16 + lq * 4;
      uint2 hp; hp.x = pack2(hv[0], hv[1]); hp.y = pack2(hv[2], hv[3]);
      if (lb < 8)
        *(uint2*)&hwr[(u0 >> 5) * 512 + (((u0 >> 3) & 3) * 16 + lb) * 8 + (u0 & 7)] = hp;
      osv[q] = make_float4(hv[0], hv[1], hv[2], hv[3]);
    }
#pragma unroll
    for (int kc = 0; kc < 8; ++kc) Be[kc] = Bn[kc];
    __syncthreads();
    if (lb < 8){
#pragma unroll
      for (int q = 0; q < NQ; ++q){
        const int u0 = v * 32 + q * 16 + lq * 4;
        *(float4*)(out + (size_t)(b0 + lb) * (T_N * D_N) + t * D_N + u0) = osv[q];
      }
    }
  }
}

extern "C" void kernel_launch(void* const* d_in, const int* in_sizes, int n_in,
                              void* d_out, int out_size, void* d_ws, size_t ws_size,
                              hipStream_t stream){
  const float* x    = (const float*)d_in[0];
  const float* eWih = (const float*)d_in[1];
  const float* eWhh = (const float*)d_in[2];
  const float* ebih = (const float*)d_in[3];
  const float* ebhh = (const float*)d_in[4];
  const float* dWih = (const float*)d_in[5];
  const float* dWhh = (const float*)d_in[6];
  const float* dbih = (const float*)d_in[7];
  const float* dbhh = (const float*)d_in[8];
  float* out = (float*)d_out;

  char* w = (char*)d_ws;
  size_t off = 0;
  auto carve = [&](size_t bytes) -> void* { void* p = w + off; off = (off + bytes + 255) & ~(size_t)255; return p; };
  u16*   xb    = (u16*)carve((size_t)B_N * T_N * D_N * 2);          // x in bf16
  u16*   WihEp = (u16*)carve((size_t)4 * H_N * D_N * 2);            // permuted enc Wih (UB=6,VB=2)
  u16*   WhhEp = (u16*)carve((size_t)4 * H_N * H_N * 2);            // permuted enc Whh (UB=6,VB=2)
  u16*   Wcat  = (u16*)carve((size_t)4 * D_N * 384 * 2);            // permuted [WihD|WhhD] 384-k rows
  float* bE    = (float*)carve((size_t)4 * H_N * 4);
  float* bD    = (float*)carve((size_t)4 * D_N * 4);
  u16*   xpE   = (u16*)carve((size_t)T_N * B_N * 4 * H_N * 2);      // [T][B][4H] permuted, bf16
  u16*   enc   = (u16*)carve((size_t)T_N * B_N * H_N * 2);          // encoded [T][B][H] bf16
  (void)ws_size; (void)in_sizes; (void)n_in; (void)out_size;

  hipLaunchKernelGGL(k_cvt, dim3((B_N * T_N * D_N) / 1024), dim3(256), 0, stream, x, xb, B_N * T_N * D_N);
  hipLaunchKernelGGL(k_permW, dim3(1024), dim3(128), 0, stream, eWih, WihEp, 128, 6, 2, 128, 0);
  hipLaunchKernelGGL(k_permW, dim3(1024), dim3(128), 0, stream, eWhh, WhhEp, 256, 6, 2, 256, 0);
  hipLaunchKernelGGL(k_permW, dim3(512),  dim3(128), 0, stream, dWih, Wcat, 256, 5, 2, 384, 0);
  hipLaunchKernelGGL(k_permW, dim3(512),  dim3(128), 0, stream, dWhh, Wcat, 128, 5, 2, 384, 256);
  hipLaunchKernelGGL(k_permB, dim3(1), dim3(256), 0, stream, ebih, ebhh, bE, 1024, 6, 2);
  hipLaunchKernelGGL(k_permB, dim3(1), dim3(256), 0, stream, dbih, dbhh, bD, 512, 5, 2);

  // enc x-proj: [65536,1024] = xb @ WihEp^T, stored [t][b][4H] permuted
  hipLaunchKernelGGL(k_xproj, dim3(1024, 16), dim3(256), 0, stream, xb, WihEp, bE, xpE);
  // enc recurrence: 4 waves 1/SIMD, F_REG=93 (372 regs) + F_LDS=35; LDS 159744 B
  hipLaunchKernelGGL(k_renc, dim3(32), dim3(256),
                     2 * 8 * 512 * 2 + 4 * 35 * 512 * 2, stream, WhhEp, xpE, enc);
  // dec recurrence (fused xprojD): 4 waves, 96 frags/wave (72 reg + 24 LDS); LDS 106496 B
  hipLaunchKernelGGL(k_rdec, dim3(32), dim3(256),
                     2 * 4 * 512 * 2 + 4 * 24 * 512 * 2, stream, Wcat, bD, enc, out);
}